// Round 4
// baseline (352.705 us; speedup 1.0000x reference)
//
#include <hip/hip_runtime.h>
#include <hip/hip_bf16.h>

// Problem geometry
#define E_CNT  256
#define D_IN   15
#define HDIM   128
#define BATCH  8192
#define CPE    (BATCH / 32)         // 256 chunks of 32 rows per expert
#define BPE    3                    // blocks per expert (grid = 768 = 3/CU exactly)
#define SW2    136                  // w2t row stride in shorts (272B = 17*16B aligned)
#define NL2E   -1.44269504088896341f

typedef float f32x16 __attribute__((ext_vector_type(16)));
typedef short bf16x8 __attribute__((ext_vector_type(8)));
typedef unsigned int uint4v __attribute__((ext_vector_type(4)));

#define MFMA(a, b, c) __builtin_amdgcn_mfma_f32_32x32x16_bf16((a), (b), (c), 0, 0, 0)

// bf16 via round-half-up on the bit pattern: 2 integer ops, no NaN path needed
// (all values here are finite). ~1ulp vs RNE.
static __device__ inline unsigned short f2bf_rnd(float f) {
    unsigned u = __builtin_bit_cast(unsigned, f);
    return (unsigned short)((u + 0x8000u) >> 16);
}

// sigmoid given pre-scaled input az = -z*log2(e): s = rcp(1 + 2^az).
// Correct limits: az->-inf => 1; az->+inf => rcp(inf)=0.
static __device__ inline float sg(float az) {
    float e = __builtin_amdgcn_exp2f(az);
    return __builtin_amdgcn_rcpf(1.0f + e);
}

// pack two floats to bf16 pair (lo in low half) with round-half-up: 4 VALU.
static __device__ inline unsigned pack2(float lo, float hi_) {
    unsigned a = __builtin_bit_cast(unsigned, lo);
    unsigned b = __builtin_bit_cast(unsigned, hi_);
    return ((a + 0x8000u) >> 16) | ((b + 0x8000u) & 0xffff0000u);
}

// v_permlane32_swap_b32 a, b:
// after: a = {lanes<32: a_lo, lanes>=32: b_lo}; b = {lanes<32: a_hi, lanes>=32: b_hi}
static __device__ inline void pl32swap(unsigned &a, unsigned &b) {
#if __has_builtin(__builtin_amdgcn_permlane32_swap)
    auto r = __builtin_amdgcn_permlane32_swap(a, b, false, false);
    a = (unsigned)r[0];
    b = (unsigned)r[1];
#else
    asm volatile("v_permlane32_swap_b32 %0, %1" : "+v"(a), "+v"(b));
#endif
}

static __device__ inline f32x16 zero16() {
    f32x16 z;
#pragma unroll
    for (int i = 0; i < 16; ++i) z[i] = 0.0f;
    return z;
}

// From a 32x32 C-tile accumulator (col = lane&31 = batch, row = (reg&3)+8*(reg>>2)+4*(lane>>5))
// holding pre-scaled pre-activations, apply sigmoid and produce the two B-frags
// (k = 16t + (lane>>5)*8 + j) covering rows 0..15 (f0) and 16..31 (f1).
static __device__ inline void sig_pack(const f32x16 a, bf16x8 &f0, bf16x8 &f1) {
    unsigned s01 = pack2(sg(a[0]),  sg(a[1]));   // rows (0,1)+4hi
    unsigned s23 = pack2(sg(a[2]),  sg(a[3]));   // rows (2,3)+4hi
    unsigned s45 = pack2(sg(a[4]),  sg(a[5]));   // rows (8,9)+4hi
    unsigned s67 = pack2(sg(a[6]),  sg(a[7]));   // rows (10,11)+4hi
    unsigned s89 = pack2(sg(a[8]),  sg(a[9]));   // rows (16,17)+4hi
    unsigned sAB = pack2(sg(a[10]), sg(a[11]));  // rows (18,19)+4hi
    unsigned sCD = pack2(sg(a[12]), sg(a[13]));  // rows (24,25)+4hi
    unsigned sEF = pack2(sg(a[14]), sg(a[15]));  // rows (26,27)+4hi
    pl32swap(s01, s45);
    pl32swap(s23, s67);
    pl32swap(s89, sCD);
    pl32swap(sAB, sEF);
    uint4v t0 = {s01, s23, s45, s67};
    uint4v t1 = {s89, sAB, sCD, sEF};
    f0 = __builtin_bit_cast(bf16x8, t0);
    f1 = __builtin_bit_cast(bf16x8, t1);
}

// x[B][15] f32 -> xbf[B][16] bf16 with slot 15 = 1.0 (b1 partner)
__global__ __launch_bounds__(256)
void prep_x_kernel(const float* __restrict__ x, unsigned short* __restrict__ xbf)
{
    int i = blockIdx.x * 256 + threadIdx.x;
    if (i >= BATCH * 16) return;
    int row = i >> 4, k = i & 15;
    float v = (k < D_IN) ? x[row * D_IN + k] : 1.0f;
    xbf[i] = f2bf_rnd(v);
}

// Transposed-orientation MFMA MLP; activations live in registers only.
// W1,b1,W2,b2 staged pre-scaled by -log2(e) so sigmoid needs no multiply.
//   L1: a1 = mfma(W1A(reg), xT)            (K=16: 15 inputs + b1 slot)
//   L2: a2 = mfma(W2T(lds), h1T(reg))      (8 K-steps + b2 K-step via B2A)
//   L3: out = mfma(W3A(reg), h2T(reg))     (8 K-steps) + b3 at store
__global__ __launch_bounds__(256, 3)
void mlp256_kernel(const float* __restrict__ x, const unsigned short* __restrict__ xbf,
                   const float* __restrict__ W1, const float* __restrict__ b1,
                   const float* __restrict__ W2, const float* __restrict__ b2,
                   const float* __restrict__ W3, const float* __restrict__ b3,
                   float* __restrict__ dst, int use_xbf, int transposed)
{
    __shared__ __align__(16) unsigned short w2t[HDIM * SW2];

    const int tid  = threadIdx.x;
    const int wave = tid >> 6;
    const int lane = tid & 63;
    const int l31  = lane & 31;
    const int hi   = lane >> 5;

    // XCD-grouped mapping: the 3 blocks of an expert share bid%8 (same XCD
    // under round-robin dispatch) so W2 is fetched into one L2.
    const int bid = blockIdx.x;              // grid = 768
    const int e   = (bid & 7) + 8 * ((bid >> 3) & 31);
    const int rg  = bid >> 8;                // 0..2; this block takes chunks c%3==rg

    const float* w1p = W1 + e * (D_IN * HDIM);
    const float* b1p = b1 + e * HDIM;
    const float* w2p = W2 + e * (HDIM * HDIM);
    const float* b2p = b2 + e * HDIM;
    const float* w3p = W3 + e * HDIM;
    const float  b3v = b3[e];

    // ---- stage W2^T scaled by NL2E (coalesced reads, scattered b16 writes; prologue-only) ----
    for (int i = tid; i < HDIM * HDIM; i += 256) {
        int h = i & 127, k = i >> 7;                 // h = out row, k = in col
        w2t[h * SW2 + k] = f2bf_rnd(w2p[k * HDIM + h] * NL2E);
    }

    // ---- persistent register fragments ----
    // W1A[mf]: rows h = mf*32+l31, k = hi*8+j; k==15 slot carries b1; all scaled.
    bf16x8 W1A[4];
#pragma unroll
    for (int mf = 0; mf < 4; ++mf) {
        int h = mf * 32 + l31;
#pragma unroll
        for (int j = 0; j < 8; ++j) {
            int k = hi * 8 + j;
            float v = (k < D_IN) ? w1p[k * HDIM + h] : b1p[h];
            W1A[mf][j] = (short)f2bf_rnd(v * NL2E);
        }
    }
    // b2 as extra K-step: A holds NL2E*b2[h] at k'==0, B (ONEB) holds 1.0 at k'==0
    bf16x8 B2A[4];
#pragma unroll
    for (int mf = 0; mf < 4; ++mf) {
#pragma unroll
        for (int j = 0; j < 8; ++j) B2A[mf][j] = 0;
        if (hi == 0) B2A[mf][0] = (short)f2bf_rnd(b2p[mf * 32 + l31] * NL2E);
    }
    bf16x8 ONEB;
#pragma unroll
    for (int j = 0; j < 8; ++j) ONEB[j] = 0;
    if (hi == 0) ONEB[0] = (short)0x3F80;            // 1.0 bf16
    // W3A[ks]: only row o==0 (l31==0) nonzero; unscaled.
    bf16x8 W3A[8];
#pragma unroll
    for (int ks = 0; ks < 8; ++ks) {
#pragma unroll
        for (int j = 0; j < 8; ++j) W3A[ks][j] = 0;
        if (l31 == 0) {
#pragma unroll
            for (int j = 0; j < 8; ++j)
                W3A[ks][j] = (short)f2bf_rnd(w3p[ks * 16 + hi * 8 + j]);
        }
    }

    __syncthreads();   // w2t staged; waves independent from here

    // chunk schedule: c = rg + 3*(wave + 4*j)  (block picks c%3==rg, waves interleave)
    for (int c = rg + 3 * wave; c < CPE; c += 12) {
        const int r0 = c * 32;
        const int bb = r0 + l31;

        // x B-frag: col b = l31, k = hi*8+j (slot 15 = 1.0)
        bf16x8 XB;
        if (use_xbf) {
            XB = *reinterpret_cast<const bf16x8*>(xbf + (size_t)bb * 16 + hi * 8);
        } else {
            const float* xp = x + (size_t)bb * D_IN;
#pragma unroll
            for (int j = 0; j < 8; ++j) {
                int k = hi * 8 + j;
                XB[j] = (short)f2bf_rnd((k < D_IN) ? xp[k] : 1.0f);
            }
        }

        // ---- layer 1 ----
        f32x16 acc1[4];
#pragma unroll
        for (int mf = 0; mf < 4; ++mf)
            acc1[mf] = MFMA(W1A[mf], XB, zero16());

        bf16x8 hb[8];
#pragma unroll
        for (int mf = 0; mf < 4; ++mf)
            sig_pack(acc1[mf], hb[2 * mf], hb[2 * mf + 1]);

        // ---- layer 2 (8 K-steps + bias step) ----
        f32x16 acc2[4];
#pragma unroll
        for (int mf = 0; mf < 4; ++mf) acc2[mf] = zero16();
#pragma unroll
        for (int ks = 0; ks < 8; ++ks) {
#pragma unroll
            for (int mf = 0; mf < 4; ++mf) {
                bf16x8 wa = *reinterpret_cast<const bf16x8*>(w2t + (mf * 32 + l31) * SW2 + ks * 16 + hi * 8);
                acc2[mf] = MFMA(wa, hb[ks], acc2[mf]);
            }
        }
#pragma unroll
        for (int mf = 0; mf < 4; ++mf)
            acc2[mf] = MFMA(B2A[mf], ONEB, acc2[mf]);

        // sigmoid -> B-frags for layer 3 (reuse hb)
#pragma unroll
        for (int mf = 0; mf < 4; ++mf)
            sig_pack(acc2[mf], hb[2 * mf], hb[2 * mf + 1]);

        // ---- layer 3 ----
        f32x16 acc3 = zero16();
#pragma unroll
        for (int ks = 0; ks < 8; ++ks)
            acc3 = MFMA(W3A[ks], hb[ks], acc3);

        if (hi == 0) {
            float v = acc3[0] + b3v;   // row 0 = reg 0, hi==0 lanes
            if (transposed) dst[(size_t)e * BATCH + r0 + l31] = v;          // coalesced
            else            dst[(size_t)(r0 + l31) * E_CNT + e] = v;        // fallback
        }
    }
}

// wsT[e][b] (256 x 8192) -> out[b][e] (8192 x 256), 64x64 LDS tiles
__global__ __launch_bounds__(256)
void transpose_out_kernel(const float* __restrict__ wsT, float* __restrict__ out)
{
    __shared__ float tile[64][65];
    const int tx = threadIdx.x & 63;
    const int ty = threadIdx.x >> 6;
    const int b0 = blockIdx.x * 64;
    const int e0 = blockIdx.y * 64;
#pragma unroll
    for (int r = ty; r < 64; r += 4)
        tile[r][tx] = wsT[(size_t)(e0 + r) * BATCH + b0 + tx];
    __syncthreads();
#pragma unroll
    for (int r = ty; r < 64; r += 4)
        out[(size_t)(b0 + r) * E_CNT + e0 + tx] = tile[tx][r];
}

extern "C" void kernel_launch(void* const* d_in, const int* in_sizes, int n_in,
                              void* d_out, int out_size, void* d_ws, size_t ws_size,
                              hipStream_t stream) {
    const float* x  = (const float*)d_in[0];
    const float* W1 = (const float*)d_in[1];
    const float* b1 = (const float*)d_in[2];
    const float* W2 = (const float*)d_in[3];
    const float* b2 = (const float*)d_in[4];
    const float* W3 = (const float*)d_in[5];
    const float* b3 = (const float*)d_in[6];
    float* out = (float*)d_out;

    const size_t XBF_BYTES = (size_t)BATCH * 16 * sizeof(unsigned short);  // 256 KB
    const size_t WST_BYTES = (size_t)E_CNT * BATCH * sizeof(float);        // 8 MB

    const bool have_xbf = ws_size >= XBF_BYTES + WST_BYTES;
    const bool have_wst = ws_size >= WST_BYTES;

    unsigned short* xbf = (unsigned short*)d_ws;
    float* wsT = have_xbf ? (float*)((char*)d_ws + XBF_BYTES) : (float*)d_ws;

    if (have_xbf)
        prep_x_kernel<<<dim3((BATCH * 16 + 255) / 256), dim3(256), 0, stream>>>(x, xbf);

    if (have_wst) {
        mlp256_kernel<<<dim3(E_CNT * BPE), dim3(256), 0, stream>>>(
            x, xbf, W1, b1, W2, b2, W3, b3, wsT, have_xbf ? 1 : 0, 1);
        transpose_out_kernel<<<dim3(BATCH / 64, E_CNT / 64), dim3(256), 0, stream>>>(
            wsT, out);
    } else {
        mlp256_kernel<<<dim3(E_CNT * BPE), dim3(256), 0, stream>>>(
            x, xbf, W1, b1, W2, b2, W3, b3, out, 0, 0);
    }
}

// Round 5
// 193.209 us; speedup vs baseline: 1.8255x; 1.8255x over previous
//
#include <hip/hip_runtime.h>
#include <hip/hip_bf16.h>

// Problem geometry
#define E_CNT  256
#define D_IN   15
#define HDIM   128
#define BATCH  8192
#define SW1    24                   // w1t row stride in shorts (48B)
#define SW2    152                  // w2t row stride in shorts (304B): 128 W2T + b2@128 + 0-pad
#define NL2E   -1.44269504088896341f

typedef float f32x16 __attribute__((ext_vector_type(16)));
typedef short bf16x8 __attribute__((ext_vector_type(8)));
typedef unsigned int uint4v __attribute__((ext_vector_type(4)));

#define MFMA(a, b, c) __builtin_amdgcn_mfma_f32_32x32x16_bf16((a), (b), (c), 0, 0, 0)

// bf16 via round-half-up on the bit pattern: 2 integer ops (values finite here).
static __device__ inline unsigned short f2bf_rnd(float f) {
    unsigned u = __builtin_bit_cast(unsigned, f);
    return (unsigned short)((u + 0x8000u) >> 16);
}

// sigmoid with pre-scaled input az = -z*log2(e): s = rcp(1 + 2^az).
static __device__ inline float sg(float az) {
    float e = __builtin_amdgcn_exp2f(az);
    return __builtin_amdgcn_rcpf(1.0f + e);
}

// pack two floats to a bf16 pair (lo in low half), round-half-up: 5 VALU.
static __device__ inline unsigned pack2(float lo, float hi_) {
    unsigned a = __builtin_bit_cast(unsigned, lo);
    unsigned b = __builtin_bit_cast(unsigned, hi_);
    return ((a + 0x8000u) >> 16) | ((b + 0x8000u) & 0xffff0000u);
}

// v_permlane32_swap_b32 a, b:
// after: a = {lanes<32: a_lo, lanes>=32: b_lo}; b = {lanes<32: a_hi, lanes>=32: b_hi}
static __device__ inline void pl32swap(unsigned &a, unsigned &b) {
#if __has_builtin(__builtin_amdgcn_permlane32_swap)
    auto r = __builtin_amdgcn_permlane32_swap(a, b, false, false);
    a = (unsigned)r[0];
    b = (unsigned)r[1];
#else
    asm volatile("v_permlane32_swap_b32 %0, %1" : "+v"(a), "+v"(b));
#endif
}

static __device__ inline f32x16 zero16() {
    f32x16 z;
#pragma unroll
    for (int i = 0; i < 16; ++i) z[i] = 0.0f;
    return z;
}

// From a 32x32 C-tile accumulator (col = lane&31 = batch, row = (reg&3)+8*(reg>>2)+4*(lane>>5))
// holding pre-scaled pre-activations, apply sigmoid and produce two B-frags
// (k = 16t + (lane>>5)*8 + j) covering tile rows 0..15 (f0) and 16..31 (f1).
static __device__ inline void sig_pack(const f32x16 a, bf16x8 &f0, bf16x8 &f1) {
    unsigned s01 = pack2(sg(a[0]),  sg(a[1]));
    unsigned s23 = pack2(sg(a[2]),  sg(a[3]));
    unsigned s45 = pack2(sg(a[4]),  sg(a[5]));
    unsigned s67 = pack2(sg(a[6]),  sg(a[7]));
    unsigned s89 = pack2(sg(a[8]),  sg(a[9]));
    unsigned sAB = pack2(sg(a[10]), sg(a[11]));
    unsigned sCD = pack2(sg(a[12]), sg(a[13]));
    unsigned sEF = pack2(sg(a[14]), sg(a[15]));
    pl32swap(s01, s45);
    pl32swap(s23, s67);
    pl32swap(s89, sCD);
    pl32swap(sAB, sEF);
    uint4v t0 = {s01, s23, s45, s67};
    uint4v t1 = {s89, sAB, sCD, sEF};
    f0 = __builtin_bit_cast(bf16x8, t0);
    f1 = __builtin_bit_cast(bf16x8, t1);
}

// x[B][15] f32 -> xbf[B][16] bf16 with slot 15 = 1.0 (b1 partner)
__global__ __launch_bounds__(256)
void prep_x_kernel(const float* __restrict__ x, unsigned short* __restrict__ xbf)
{
    int i = blockIdx.x * 256 + threadIdx.x;
    if (i >= BATCH * 16) return;
    int row = i >> 4, k = i & 15;
    float v = (k < D_IN) ? x[row * D_IN + k] : 1.0f;
    xbf[i] = f2bf_rnd(v);
}

// Dual-chunk transposed-orientation MFMA MLP. Two 32-row batch chunks (A,B)
// share every weight-fragment LDS read. L3 is accumulated per mf-tile so h2
// fragments die immediately (register peak ~190 < 256 cap at 2 waves/EU).
__global__ __launch_bounds__(256, 2)
void mlp256_kernel(const float* __restrict__ x, const unsigned short* __restrict__ xbf,
                   const float* __restrict__ W1, const float* __restrict__ b1,
                   const float* __restrict__ W2, const float* __restrict__ b2,
                   const float* __restrict__ W3, const float* __restrict__ b3,
                   float* __restrict__ dst, int use_xbf, int transposed)
{
    __shared__ __align__(16) unsigned short w1t[HDIM * SW1];   // W1^T (+b1 at k=15), scaled
    __shared__ __align__(16) unsigned short w2t[HDIM * SW2];   // W2^T scaled + b2 pad at 128
    __shared__ __align__(16) unsigned short w3l[HDIM];         // w3 (unscaled)

    const int tid  = threadIdx.x;
    const int wave = tid >> 6;
    const int lane = tid & 63;
    const int l31  = lane & 31;
    const int hi   = lane >> 5;

    // grid = 512: e = bid&255, rg = bid>>8. Blocks (b, b+256) share bid%8 -> same XCD
    // under round-robin dispatch, so one expert's W2 lives in one L2.
    const int bid = blockIdx.x;
    const int e   = bid & 255;
    const int rg  = bid >> 8;                 // 0..1: rows [rg*4096, rg*4096+4096)

    const float* w1p = W1 + e * (D_IN * HDIM);
    const float* b1p = b1 + e * HDIM;
    const float* w2p = W2 + e * (HDIM * HDIM);
    const float* b2p = b2 + e * HDIM;
    const float* w3p = W3 + e * HDIM;
    const float  b3v = b3[e];

    // ---- stage weights (prologue only) ----
    for (int i = tid; i < HDIM * 16; i += 256) {
        int h = i & 127, k = i >> 7;
        float v = (k < D_IN) ? w1p[k * HDIM + h] : b1p[h];
        w1t[h * SW1 + k] = f2bf_rnd(v * NL2E);
    }
    for (int i = tid; i < HDIM * HDIM; i += 256) {
        int h = i & 127, k = i >> 7;
        w2t[h * SW2 + k] = f2bf_rnd(w2p[k * HDIM + h] * NL2E);
    }
    for (int i = tid; i < HDIM * 16; i += 256) {
        int h = i >> 4, kk = i & 15;
        w2t[h * SW2 + 128 + kk] = (kk == 0) ? f2bf_rnd(b2p[h] * NL2E) : (unsigned short)0;
    }
    for (int i = tid; i < HDIM; i += 256) w3l[i] = f2bf_rnd(w3p[i]);

    bf16x8 ONEB;   // B-frag with 1.0 at k'==0 (partners the b2 K-step)
#pragma unroll
    for (int j = 0; j < 8; ++j) ONEB[j] = 0;
    if (hi == 0) ONEB[0] = (short)0x3F80;

    const bool sel0 = (l31 == 0);   // W3 A-frag: only output-row 0 lanes carry data

    __syncthreads();   // weights staged; waves independent from here

    // per wave: 16 dual-iterations covering 32 chunks (1024 rows)
    for (int d = 0; d < 16; ++d) {
        const int c0 = rg * 128 + wave * 32 + 2 * d;
        const int rA = c0 * 32 + l31;            // chunk A rows
        const int rB = rA + 32;                  // chunk B rows

        // x B-frags (col = l31, k = hi*8+j, slot 15 = 1.0)
        bf16x8 XA, XBv;
        if (use_xbf) {
            XA  = *reinterpret_cast<const bf16x8*>(xbf + (size_t)rA * 16 + hi * 8);
            XBv = *reinterpret_cast<const bf16x8*>(xbf + (size_t)rB * 16 + hi * 8);
        } else {
            const float* xa = x + (size_t)rA * D_IN;
            const float* xb = x + (size_t)rB * D_IN;
#pragma unroll
            for (int j = 0; j < 8; ++j) {
                int k = hi * 8 + j;
                XA[j]  = (short)f2bf_rnd((k < D_IN) ? xa[k] : 1.0f);
                XBv[j] = (short)f2bf_rnd((k < D_IN) ? xb[k] : 1.0f);
            }
        }

        // ---- layer 1 (W1 frag read shared by A and B) ----
        f32x16 a1A[4], a1B[4];
#pragma unroll
        for (int mf = 0; mf < 4; ++mf) {
            bf16x8 wa = *reinterpret_cast<const bf16x8*>(w1t + (mf * 32 + l31) * SW1 + hi * 8);
            a1A[mf] = MFMA(wa, XA,  zero16());
            a1B[mf] = MFMA(wa, XBv, zero16());
        }

        bf16x8 hA[8], hB[8];
#pragma unroll
        for (int mf = 0; mf < 4; ++mf) {
            sig_pack(a1A[mf], hA[2 * mf], hA[2 * mf + 1]);
            sig_pack(a1B[mf], hB[2 * mf], hB[2 * mf + 1]);
        }

        // ---- layer 2 + partial layer 3, per mf-tile ----
        f32x16 o3A = zero16(), o3B = zero16();
#pragma unroll
        for (int mf = 0; mf < 4; ++mf) {
            // init accumulators from the b2 bias K-step (shared bias frag)
            bf16x8 wb = *reinterpret_cast<const bf16x8*>(w2t + (mf * 32 + l31) * SW2 + 128 + hi * 8);
            f32x16 c2A = MFMA(wb, ONEB, zero16());
            f32x16 c2B = MFMA(wb, ONEB, zero16());
#pragma unroll
            for (int ks = 0; ks < 8; ++ks) {
                bf16x8 wa = *reinterpret_cast<const bf16x8*>(w2t + (mf * 32 + l31) * SW2 + ks * 16 + hi * 8);
                c2A = MFMA(wa, hA[ks], c2A);
                c2B = MFMA(wa, hB[ks], c2B);
            }
            // sigmoid -> h2 fragments for this mf-tile (rows 32mf..32mf+31 = ks 2mf,2mf+1)
            bf16x8 g0A, g1A, g0B, g1B;
            sig_pack(c2A, g0A, g1A);
            sig_pack(c2B, g0B, g1B);
            // layer-3 partial: W3 A-frags (broadcast read + zero for l31!=0)
#pragma unroll
            for (int t = 0; t < 2; ++t) {
                int ks = 2 * mf + t;
                bf16x8 w3f = *reinterpret_cast<const bf16x8*>(w3l + ks * 16 + hi * 8);
                uint4v u = __builtin_bit_cast(uint4v, w3f);
                if (!sel0) { u[0] = 0; u[1] = 0; u[2] = 0; u[3] = 0; }
                w3f = __builtin_bit_cast(bf16x8, u);
                o3A = MFMA(w3f, (t ? g1A : g0A), o3A);
                o3B = MFMA(w3f, (t ? g1B : g0B), o3B);
            }
        }

        if (hi == 0) {
            float vA = o3A[0] + b3v;   // row 0 = reg 0, hi==0 lanes
            float vB = o3B[0] + b3v;
            if (transposed) {
                dst[(size_t)e * BATCH + rA] = vA;
                dst[(size_t)e * BATCH + rB] = vB;
            } else {
                dst[(size_t)rA * E_CNT + e] = vA;
                dst[(size_t)rB * E_CNT + e] = vB;
            }
        }
    }
}

// wsT[e][b] (256 x 8192) -> out[b][e] (8192 x 256), 64x64 LDS tiles
__global__ __launch_bounds__(256)
void transpose_out_kernel(const float* __restrict__ wsT, float* __restrict__ out)
{
    __shared__ float tile[64][65];
    const int tx = threadIdx.x & 63;
    const int ty = threadIdx.x >> 6;
    const int b0 = blockIdx.x * 64;
    const int e0 = blockIdx.y * 64;
#pragma unroll
    for (int r = ty; r < 64; r += 4)
        tile[r][tx] = wsT[(size_t)(e0 + r) * BATCH + b0 + tx];
    __syncthreads();
#pragma unroll
    for (int r = ty; r < 64; r += 4)
        out[(size_t)(b0 + r) * E_CNT + e0 + tx] = tile[tx][r];
}

extern "C" void kernel_launch(void* const* d_in, const int* in_sizes, int n_in,
                              void* d_out, int out_size, void* d_ws, size_t ws_size,
                              hipStream_t stream) {
    const float* x  = (const float*)d_in[0];
    const float* W1 = (const float*)d_in[1];
    const float* b1 = (const float*)d_in[2];
    const float* W2 = (const float*)d_in[3];
    const float* b2 = (const float*)d_in[4];
    const float* W3 = (const float*)d_in[5];
    const float* b3 = (const float*)d_in[6];
    float* out = (float*)d_out;

    const size_t XBF_BYTES = (size_t)BATCH * 16 * sizeof(unsigned short);  // 256 KB
    const size_t WST_BYTES = (size_t)E_CNT * BATCH * sizeof(float);        // 8 MB

    const bool have_xbf = ws_size >= XBF_BYTES + WST_BYTES;
    const bool have_wst = ws_size >= WST_BYTES;

    unsigned short* xbf = (unsigned short*)d_ws;
    float* wsT = have_xbf ? (float*)((char*)d_ws + XBF_BYTES) : (float*)d_ws;

    if (have_xbf)
        prep_x_kernel<<<dim3((BATCH * 16 + 255) / 256), dim3(256), 0, stream>>>(x, xbf);

    if (have_wst) {
        mlp256_kernel<<<dim3(E_CNT * 2), dim3(256), 0, stream>>>(
            x, xbf, W1, b1, W2, b2, W3, b3, wsT, have_xbf ? 1 : 0, 1);
        transpose_out_kernel<<<dim3(BATCH / 64, E_CNT / 64), dim3(256), 0, stream>>>(
            wsT, out);
    } else {
        mlp256_kernel<<<dim3(E_CNT * 2), dim3(256), 0, stream>>>(
            x, xbf, W1, b1, W2, b2, W3, b3, out, 0, 0);
    }
}